// Round 1
// baseline (118.893 us; speedup 1.0000x reference)
//
#include <hip/hip_runtime.h>
#include <math.h>

constexpr int NATOMS = 1024;

__device__ __forceinline__ float wred(float v) {
#pragma unroll
    for (int o = 32; o > 0; o >>= 1) v += __shfl_xor(v, o, 64);
    return v;
}

__global__ __launch_bounds__(256) void rmsd_kernel(
    const float* __restrict__ inp, const float* __restrict__ tgt,
    const int* __restrict__ natoms, float* __restrict__ out)
{
    const int b = blockIdx.x;
    const int t = threadIdx.x;
    const int n = natoms[b];

    // thread t owns atoms [4t, 4t+4): 12 contiguous floats at float4 index 3t
    const float4* __restrict__ x4 = (const float4*)(inp + (size_t)b * (3 * NATOMS)) + t * 3;
    const float4* __restrict__ y4 = (const float4*)(tgt + (size_t)b * (3 * NATOMS)) + t * 3;

    float4 xa = x4[0], xb = x4[1], xc = x4[2];
    float4 ya = y4[0], yb = y4[1], yc = y4[2];

    // acc: 0-2 sum x, 3-5 sum y, 6-14 sum x_i*y_j, 15 sum|x|^2, 16 sum|y|^2
    float acc[17];
#pragma unroll
    for (int i = 0; i < 17; ++i) acc[i] = 0.f;

    const float X[4][3] = {{xa.x,xa.y,xa.z},{xa.w,xb.x,xb.y},{xb.z,xb.w,xc.x},{xc.y,xc.z,xc.w}};
    const float Y[4][3] = {{ya.x,ya.y,ya.z},{ya.w,yb.x,yb.y},{yb.z,yb.w,yc.x},{yc.y,yc.z,yc.w}};
    const int base = t * 4;
#pragma unroll
    for (int j = 0; j < 4; ++j) {
        const float m = (base + j < n) ? 1.f : 0.f;
        const float x0 = X[j][0]*m, x1 = X[j][1]*m, x2 = X[j][2]*m;
        const float y0 = Y[j][0]*m, y1 = Y[j][1]*m, y2 = Y[j][2]*m;
        acc[0] += x0; acc[1] += x1; acc[2] += x2;
        acc[3] += y0; acc[4] += y1; acc[5] += y2;
        acc[6]  += x0*y0; acc[7]  += x0*y1; acc[8]  += x0*y2;
        acc[9]  += x1*y0; acc[10] += x1*y1; acc[11] += x1*y2;
        acc[12] += x2*y0; acc[13] += x2*y1; acc[14] += x2*y2;
        acc[15] += x0*x0 + x1*x1 + x2*x2;
        acc[16] += y0*y0 + y1*y1 + y2*y2;
    }

#pragma unroll
    for (int i = 0; i < 17; ++i) acc[i] = wred(acc[i]);

    __shared__ float red[4][17];
    const int wave = t >> 6, lane = t & 63;
    if (lane == 0) {
#pragma unroll
        for (int i = 0; i < 17; ++i) red[wave][i] = acc[i];
    }
    __syncthreads();

    if (t == 0) {
        double s[17];
#pragma unroll
        for (int i = 0; i < 17; ++i)
            s[i] = (double)red[0][i] + (double)red[1][i] + (double)red[2][i] + (double)red[3][i];
        const double nd = (double)n;

        // centered covariance R[i][j] = sum x_i y_j - (sum x_i)(sum y_j)/n
        double R[3][3];
        for (int i = 0; i < 3; ++i)
            for (int j = 0; j < 3; ++j)
                R[i][j] = s[6 + i*3 + j] - s[i] * s[3 + j] / nd;
        const double ex = s[15] - (s[0]*s[0] + s[1]*s[1] + s[2]*s[2]) / nd;
        const double ey = s[16] - (s[3]*s[3] + s[4]*s[4] + s[5]*s[5]) / nd;

        const double detR =
              R[0][0]*(R[1][1]*R[2][2] - R[1][2]*R[2][1])
            - R[0][1]*(R[1][0]*R[2][2] - R[1][2]*R[2][0])
            + R[0][2]*(R[1][0]*R[2][1] - R[1][1]*R[2][0]);

        // K = R^T R (symmetric PSD); eigenvalues are squared singular values
        double K00=0, K01=0, K02=0, K11=0, K12=0, K22=0;
        for (int k = 0; k < 3; ++k) {
            K00 += R[k][0]*R[k][0]; K01 += R[k][0]*R[k][1]; K02 += R[k][0]*R[k][2];
            K11 += R[k][1]*R[k][1]; K12 += R[k][1]*R[k][2]; K22 += R[k][2]*R[k][2];
        }

        // analytic symmetric 3x3 eigenvalues (trig method), f64
        const double qm = (K00 + K11 + K22) / 3.0;
        const double p1 = K01*K01 + K02*K02 + K12*K12;
        const double p2 = (K00-qm)*(K00-qm) + (K11-qm)*(K11-qm) + (K22-qm)*(K22-qm) + 2.0*p1;
        double e1, e2, e3;
        if (p2 <= 1e-30) {
            e1 = e2 = e3 = qm;
        } else {
            const double p = sqrt(p2 / 6.0);
            const double inv = 1.0 / p;
            const double B00 = (K00-qm)*inv, B11 = (K11-qm)*inv, B22 = (K22-qm)*inv;
            const double B01 = K01*inv, B02 = K02*inv, B12 = K12*inv;
            const double detB =
                  B00*(B11*B22 - B12*B12)
                - B01*(B01*B22 - B12*B02)
                + B02*(B01*B12 - B11*B02);
            double r = detB * 0.5;
            r = fmin(1.0, fmax(-1.0, r));
            const double phi = acos(r) / 3.0;
            e1 = qm + 2.0*p*cos(phi);
            e3 = qm + 2.0*p*cos(phi + 2.0943951023931953);  // +2*pi/3 -> smallest
            e2 = 3.0*qm - e1 - e3;
        }
        const double S1 = sqrt(fmax(e1, 0.0));
        const double S2 = sqrt(fmax(e2, 0.0));
        const double S3 = sqrt(fmax(e3, 0.0));
        const double dsg = (detR < 0.0) ? -1.0 : 1.0;  // detR==0 => S3==0, sign moot
        const double sv = S1 + S2 + dsg * S3;

        const double e = ex + ey - 2.0 * sv;
        out[b] = (float)sqrt(fmax(e / nd, 1e-12));
    }
}

extern "C" void kernel_launch(void* const* d_in, const int* in_sizes, int n_in,
                              void* d_out, int out_size, void* d_ws, size_t ws_size,
                              hipStream_t stream) {
    const float* inp = (const float*)d_in[0];
    const float* tgt = (const float*)d_in[1];
    const int*   na  = (const int*)d_in[2];
    float* out = (float*)d_out;
    const int batch = in_sizes[2];  // 4096
    rmsd_kernel<<<batch, 256, 0, stream>>>(inp, tgt, na, out);
}